// Round 2
// baseline (122.409 us; speedup 1.0000x reference)
//
#include <hip/hip_runtime.h>

#define TS 20
#define BATCH 8192

typedef _Float16 half8 __attribute__((ext_vector_type(8)));
typedef float f32x4 __attribute__((ext_vector_type(4)));

__device__ __forceinline__ float fast_sig(float z) {
    return __builtin_amdgcn_rcpf(1.0f + __expf(-z));
}
__device__ __forceinline__ float fast_tanh(float z) {
    return 1.0f - 2.0f * __builtin_amdgcn_rcpf(1.0f + __expf(2.0f * z));
}

// ===================== Kernel 1: LSTM layer 1 =====================
// K layout = [h1(0:128) | x(128:144) | pad(144:160)], 5 chunks of 32.
// 8 waves; wave w owns cells [w*16, w*16+16) for all 4 gates (co-located).
// ONE barrier per timestep via double-buffered h1.
extern "C" __global__ __launch_bounds__(512, 4)
void lstm1_kernel(const float* __restrict__ x,
                  const float* __restrict__ Wih1, const float* __restrict__ Whh1,
                  const float* __restrict__ bih1, const float* __restrict__ bhh1,
                  _Float16* __restrict__ out1)   // [TS][BATCH][128] fp16
{
    __shared__ __align__(16) _Float16 A1h[2][16][136];  // row stride 272B (17 quads, odd -> bank-spread)
    __shared__ __align__(16) _Float16 A1x[16][328];     // row stride 656B (41 quads, odd)
    __shared__ __align__(16) _Float16 zpad[8];

    const int tid  = threadIdx.x;
    const int lane = tid & 63;
    const int w    = tid >> 6;
    const int lrow = lane & 15;
    const int lgrp = lane >> 4;
    const int b0   = blockIdx.x * 16;

    half8 bf1[4][5];
    float bias1[4];
#pragma unroll
    for (int g = 0; g < 4; ++g) {
        const int n = g * 128 + w * 16 + lrow;
        bias1[g] = bih1[n] + bhh1[n];
#pragma unroll
        for (int ch = 0; ch < 5; ++ch) {
            half8 v;
#pragma unroll
            for (int j = 0; j < 8; ++j) {
                const int kk = ch * 32 + lgrp * 8 + j;
                float t;
                if (kk < 128)      t = Whh1[n * 128 + kk];
                else if (kk < 144) t = Wih1[n * 16 + (kk - 128)];
                else               t = 0.0f;
                v[j] = (_Float16)t;
            }
            bf1[g][ch] = v;
        }
    }

    // stage all x for this block's 16 rows as fp16 (rows are 320 contiguous floats)
    for (int i = tid; i < 16 * 320; i += 512) {
        const int m = i / 320, k = i % 320;
        A1x[m][k] = (_Float16)x[(size_t)(b0 + m) * 320 + k];
    }
    for (int i = tid; i < 16 * 136; i += 512)
        (&A1h[0][0][0])[i] = (_Float16)0.0f;
    if (tid < 8) zpad[tid] = (_Float16)0.0f;

    float c1[4] = {0.f, 0.f, 0.f, 0.f};
    const int hh = w * 16 + lrow;
    __syncthreads();

    int cur = 0;
    for (int t = 0; t < TS; ++t) {
        const int nxt = cur ^ 1;
        const f32x4 zz = {0.f, 0.f, 0.f, 0.f};
        f32x4 z[4] = {zz, zz, zz, zz};
#pragma unroll
        for (int ch = 0; ch < 5; ++ch) {
            half8 a;
            if (ch < 4) {
                a = *(const half8*)&A1h[cur][lrow][ch * 32 + lgrp * 8];
            } else {
                const _Float16* p = (lgrp < 2) ? &A1x[lrow][t * 16 + lgrp * 8] : &zpad[0];
                a = *(const half8*)p;
            }
#pragma unroll
            for (int g = 0; g < 4; ++g)
                z[g] = __builtin_amdgcn_mfma_f32_16x16x32_f16(a, bf1[g][ch], z[g], 0, 0, 0);
        }
#pragma unroll
        for (int j = 0; j < 4; ++j) {
            const float iv = fast_sig (z[0][j] + bias1[0]);
            const float fv = fast_sig (z[1][j] + bias1[1]);
            const float gv = fast_tanh(z[2][j] + bias1[2]);
            const float ov = fast_sig (z[3][j] + bias1[3]);
            const float cn = fv * c1[j] + iv * gv;
            c1[j] = cn;
            const float h = ov * fast_tanh(cn);
            const _Float16 h16 = (_Float16)h;
            const int m = lgrp * 4 + j;
            A1h[nxt][m][hh] = h16;
            out1[((size_t)t * BATCH + b0 + m) * 128 + hh] = h16;
        }
        __syncthreads();
        cur = nxt;
    }
}

// ===================== Kernel 2: LSTM layer 2 + LN + FC =====================
// K layout = [h1(0:128) | h2(128:192)], 6 chunks of 32.
// 4 waves; wave w owns cells [w*16, w*16+16) for all 4 gates.
// h1 tile staged in LDS with XOR chunk swizzle; prefetched with async split.
extern "C" __global__ __launch_bounds__(256, 3)
void lstm2_head_kernel(const _Float16* __restrict__ out1,
                       const float* __restrict__ Wih2, const float* __restrict__ Whh2,
                       const float* __restrict__ bih2, const float* __restrict__ bhh2,
                       const float* __restrict__ gamma, const float* __restrict__ beta,
                       const float* __restrict__ W1fc, const float* __restrict__ b1fc,
                       const float* __restrict__ W2fc, const float* __restrict__ b2fc,
                       float* __restrict__ out)
{
    __shared__ __align__(16) _Float16 A2h1[2][16][128];  // 16B chunk c of row r stored at chunk c^(r&7)
    __shared__ __align__(16) _Float16 A2h2[2][16][72];   // row stride 144B (9 quads, odd)
    __shared__ float h2f[16][68];
    __shared__ float nrm[16][68];

    const int tid  = threadIdx.x;
    const int lane = tid & 63;
    const int w    = tid >> 6;      // 0..3
    const int lrow = lane & 15;
    const int lgrp = lane >> 4;
    const int b0   = blockIdx.x * 16;

    half8 bf2[4][6];
    float bias2[4];
#pragma unroll
    for (int g = 0; g < 4; ++g) {
        const int n = g * 64 + w * 16 + lrow;
        bias2[g] = bih2[n] + bhh2[n];
#pragma unroll
        for (int ch = 0; ch < 6; ++ch) {
            half8 v;
#pragma unroll
            for (int j = 0; j < 8; ++j) {
                const int kk = ch * 32 + lgrp * 8 + j;
                v[j] = (_Float16)((kk < 128) ? Wih2[n * 128 + kk]
                                             : Whh2[n * 64 + (kk - 128)]);
            }
            bf2[g][ch] = v;
        }
    }

    // zero h2(-1)
    for (int i = tid; i < 16 * 72; i += 256)
        (&A2h2[0][0][0])[i] = (_Float16)0.0f;

    // prologue: stage out1[t=0] tile (swizzled)
    {
        const int row = tid >> 4, ck = tid & 15;
        const half8 v = *(const half8*)(out1 + ((size_t)0 * BATCH + b0 + row) * 128 + ck * 8);
        *(half8*)&A2h1[0][row][((ck ^ (row & 7)) * 8)] = v;
    }
    float c2[4] = {0.f, 0.f, 0.f, 0.f};
    __syncthreads();

    int cur = 0;
    for (int t = 0; t < TS; ++t) {
        const int nxt = cur ^ 1;
        // async-split prefetch of next h1 tile: load early...
        half8 pf;
        const int prow = tid >> 4, pck = tid & 15;
        if (t + 1 < TS)
            pf = *(const half8*)(out1 + ((size_t)(t + 1) * BATCH + b0 + prow) * 128 + pck * 8);

        const f32x4 zz = {0.f, 0.f, 0.f, 0.f};
        f32x4 z[4] = {zz, zz, zz, zz};
#pragma unroll
        for (int ch = 0; ch < 6; ++ch) {
            half8 a;
            if (ch < 4) {
                const int ckr = (ch * 4 + lgrp) ^ (lrow & 7);
                a = *(const half8*)&A2h1[cur][lrow][ckr * 8];
            } else {
                a = *(const half8*)&A2h2[cur][lrow][(ch - 4) * 32 + lgrp * 8];
            }
#pragma unroll
            for (int g = 0; g < 4; ++g)
                z[g] = __builtin_amdgcn_mfma_f32_16x16x32_f16(a, bf2[g][ch], z[g], 0, 0, 0);
        }
        const int cell = w * 16 + lrow;
#pragma unroll
        for (int j = 0; j < 4; ++j) {
            const float iv = fast_sig (z[0][j] + bias2[0]);
            const float fv = fast_sig (z[1][j] + bias2[1]);
            const float gv = fast_tanh(z[2][j] + bias2[2]);
            const float ov = fast_sig (z[3][j] + bias2[3]);
            const float cn = fv * c2[j] + iv * gv;
            c2[j] = cn;
            const float h = ov * fast_tanh(cn);
            const int m = lgrp * 4 + j;
            A2h2[nxt][m][cell] = (_Float16)h;
            if (t == TS - 1) h2f[m][cell] = h;
        }
        // ...write late (into the buffer nobody reads this step)
        if (t + 1 < TS)
            *(half8*)&A2h1[nxt][prow][((pck ^ (prow & 7)) * 8)] = pf;
        __syncthreads();
        cur = nxt;
    }

    // ---- epilogue: LayerNorm + FC1(relu) + FC2 (256 threads) ----
    {
        const int m = tid >> 4, q = tid & 15;
        const float v0 = h2f[m][q * 4 + 0];
        const float v1 = h2f[m][q * 4 + 1];
        const float v2 = h2f[m][q * 4 + 2];
        const float v3 = h2f[m][q * 4 + 3];
        float s = v0 + v1 + v2 + v3;
        s += __shfl_xor(s, 1); s += __shfl_xor(s, 2);
        s += __shfl_xor(s, 4); s += __shfl_xor(s, 8);
        const float mean = s * (1.0f / 64.0f);
        const float d0 = v0 - mean, d1 = v1 - mean, d2 = v2 - mean, d3 = v3 - mean;
        float vs = d0 * d0 + d1 * d1 + d2 * d2 + d3 * d3;
        vs += __shfl_xor(vs, 1); vs += __shfl_xor(vs, 2);
        vs += __shfl_xor(vs, 4); vs += __shfl_xor(vs, 8);
        const float rstd = rsqrtf(vs * (1.0f / 64.0f) + 1e-5f);
        const int i0 = q * 4;
        nrm[m][i0 + 0] = d0 * rstd * gamma[i0 + 0] + beta[i0 + 0];
        nrm[m][i0 + 1] = d1 * rstd * gamma[i0 + 1] + beta[i0 + 1];
        nrm[m][i0 + 2] = d2 * rstd * gamma[i0 + 2] + beta[i0 + 2];
        nrm[m][i0 + 3] = d3 * rstd * gamma[i0 + 3] + beta[i0 + 3];
    }
    __syncthreads();
    {
        const int o = tid & 31;
        const int mbase = tid >> 5;   // 0..7
#pragma unroll
        for (int rr = 0; rr < 2; ++rr) {
            const int m = mbase + rr * 8;
            float acc = b1fc[o];
#pragma unroll 8
            for (int k = 0; k < 64; ++k) acc += nrm[m][k] * W1fc[o * 64 + k];
            const float hv = fmaxf(acc, 0.0f);
            float p = hv * W2fc[o];
            p += __shfl_xor(p, 1); p += __shfl_xor(p, 2);
            p += __shfl_xor(p, 4); p += __shfl_xor(p, 8); p += __shfl_xor(p, 16);
            if (o == 0) out[b0 + m] = p + b2fc[0];
        }
    }
}

extern "C" void kernel_launch(void* const* d_in, const int* in_sizes, int n_in,
                              void* d_out, int out_size, void* d_ws, size_t ws_size,
                              hipStream_t stream) {
    (void)in_sizes; (void)n_in; (void)ws_size; (void)out_size;
    const float* x_p    = (const float*)d_in[0];
    const float* Wih1_p = (const float*)d_in[1];
    const float* Whh1_p = (const float*)d_in[2];
    const float* bih1_p = (const float*)d_in[3];
    const float* bhh1_p = (const float*)d_in[4];
    const float* Wih2_p = (const float*)d_in[5];
    const float* Whh2_p = (const float*)d_in[6];
    const float* bih2_p = (const float*)d_in[7];
    const float* bhh2_p = (const float*)d_in[8];
    const float* gamma_p = (const float*)d_in[9];
    const float* beta_p  = (const float*)d_in[10];
    const float* W1_p   = (const float*)d_in[11];
    const float* b1_p   = (const float*)d_in[12];
    const float* W2_p   = (const float*)d_in[13];
    const float* b2_p   = (const float*)d_in[14];
    float* out_p = (float*)d_out;

    _Float16* out1 = (_Float16*)d_ws;   // 20*8192*128*2 = 41.9 MB

    lstm1_kernel<<<dim3(BATCH / 16), dim3(512), 0, stream>>>(
        x_p, Wih1_p, Whh1_p, bih1_p, bhh1_p, out1);
    lstm2_head_kernel<<<dim3(BATCH / 16), dim3(256), 0, stream>>>(
        out1, Wih2_p, Whh2_p, bih2_p, bhh2_p,
        gamma_p, beta_p, W1_p, b1_p, W2_p, b2_p, out_p);
}

// Round 3
// 95.233 us; speedup vs baseline: 1.2854x; 1.2854x over previous
//
#include <hip/hip_runtime.h>

#define TS 20
#define BATCH 8192

typedef _Float16 half8 __attribute__((ext_vector_type(8)));
typedef float f32x4 __attribute__((ext_vector_type(4)));

__device__ __forceinline__ float fast_sig(float z) {
    return __builtin_amdgcn_rcpf(1.0f + __expf(-z));
}
__device__ __forceinline__ float fast_tanh(float z) {
    return 1.0f - 2.0f * __builtin_amdgcn_rcpf(1.0f + __expf(2.0f * z));
}

// ===================== Kernel 1: LSTM layer 1 =====================
// BT=32 (two 16-row M-tiles interleaved per wave), 8 waves, grid=256 (1 block/CU).
// K layout = [h1(0:128) | x(128:144) | pad(144:160)], 5 chunks of 32.
// Wave w owns cells [w*16, w*16+16) for all 4 gates (i,f,g,o co-located per lane).
// h double-buffer in LDS, XOR-swizzled 16B units; ONE barrier per step.
// out1 stored coalesced (half8/thread) right after the barrier -> retires under next step.
extern "C" __global__ __launch_bounds__(512, 2)
void lstm1_kernel(const float* __restrict__ x,
                  const float* __restrict__ Wih1, const float* __restrict__ Whh1,
                  const float* __restrict__ bih1, const float* __restrict__ bhh1,
                  _Float16* __restrict__ out1)   // [TS][BATCH][128] fp16
{
    __shared__ __align__(16) _Float16 Hb[2][2][16][128];  // [buf][tile][row][cell], unit-swizzled
    __shared__ __align__(16) _Float16 Xb[32][672];        // unit ut=t*4+lgrp, stored at ut^(row&7); zero-padded

    const int tid  = threadIdx.x;
    const int lane = tid & 63;
    const int w    = tid >> 6;     // 0..7
    const int lrow = lane & 15;
    const int lgrp = lane >> 4;    // 0..3
    const int b0   = blockIdx.x * 32;

    // ---- persistent L1 weight fragments (80 VGPR) ----
    half8 bf[4][5];
    float bias[4];
#pragma unroll
    for (int g = 0; g < 4; ++g) {
        const int n = g * 128 + w * 16 + lrow;
        bias[g] = bih1[n] + bhh1[n];
#pragma unroll
        for (int ch = 0; ch < 5; ++ch) {
            half8 v;
#pragma unroll
            for (int j = 0; j < 8; ++j) {
                const int kk = ch * 32 + lgrp * 8 + j;
                float t;
                if (kk < 128)      t = Whh1[n * 128 + kk];
                else if (kk < 144) t = Wih1[n * 16 + (kk - 128)];
                else               t = 0.0f;
                v[j] = (_Float16)t;
            }
            bf[g][ch] = v;
        }
    }

    // ---- zero LDS, then stage x as fp16 (swizzled, zero-padded chunks) ----
    for (int i = tid; i < 32 * 672; i += 512) (&Xb[0][0])[i] = (_Float16)0.0f;
    for (int i = tid; i < 2 * 2 * 16 * 128; i += 512) (&Hb[0][0][0][0])[i] = (_Float16)0.0f;
    __syncthreads();
    for (int i = tid; i < 32 * 320; i += 512) {
        const int r = i / 320, k = i % 320;
        const int t = k >> 4, ii = k & 15;
        const int u = (t * 4 + (ii >> 3)) ^ (r & 7);
        Xb[r][u * 8 + (ii & 7)] = (_Float16)x[(size_t)(b0 + r) * 320 + k];
    }
    __syncthreads();

    float c1[2][4] = {{0.f,0.f,0.f,0.f},{0.f,0.f,0.f,0.f}};

    // out-store mapping: thread stores one half8 of row srow, chunk sc
    const int srow = tid >> 4;        // 0..31
    const int sc   = tid & 15;
    const int stile = srow >> 4, srr = srow & 15;
    const size_t out_off = (size_t)(b0 + srow) * 128 + sc * 8;

    for (int tt = 0; tt < 10; ++tt) {
#pragma unroll
        for (int p = 0; p < 2; ++p) {
            const int t = tt * 2 + p;
            // ---- load A-fragments: h(t-1) from Hb[p^1], x(t) from Xb ----
            half8 a[2][5];
#pragma unroll
            for (int tile = 0; tile < 2; ++tile) {
#pragma unroll
                for (int ch = 0; ch < 4; ++ch)
                    a[tile][ch] = *(const half8*)&Hb[p ^ 1][tile][lrow][(((ch << 2) | lgrp) ^ (lrow & 7)) * 8];
                const int r = tile * 16 + lrow;
                a[tile][4] = *(const half8*)&Xb[r][((t * 4 + lgrp) ^ (lrow & 7)) * 8];
            }
            // ---- MFMA: both tiles, 4 gates, bias pre-loaded in acc ----
            f32x4 z[2][4];
#pragma unroll
            for (int tile = 0; tile < 2; ++tile)
#pragma unroll
                for (int g = 0; g < 4; ++g) {
                    f32x4 acc = {bias[g], bias[g], bias[g], bias[g]};
#pragma unroll
                    for (int ch = 0; ch < 5; ++ch)
                        acc = __builtin_amdgcn_mfma_f32_16x16x32_f16(a[tile][ch], bf[g][ch], acc, 0, 0, 0);
                    z[tile][g] = acc;
                }
            // ---- activations + h(t) -> Hb[p] (swizzled b16 writes) ----
#pragma unroll
            for (int tile = 0; tile < 2; ++tile)
#pragma unroll
                for (int j = 0; j < 4; ++j) {
                    const float iv = fast_sig (z[tile][0][j]);
                    const float fv = fast_sig (z[tile][1][j]);
                    const float gv = fast_tanh(z[tile][2][j]);
                    const float ov = fast_sig (z[tile][3][j]);
                    const float cn = fv * c1[tile][j] + iv * gv;
                    c1[tile][j] = cn;
                    const float h = ov * fast_tanh(cn);
                    const int m  = (lgrp << 2) | j;
                    const int cu = ((w * 2 + (lrow >> 3)) ^ (m & 7));
                    Hb[p][tile][m][cu * 8 + (lrow & 7)] = (_Float16)h;
                }
            __syncthreads();
            // ---- coalesced out1 store for step t (retires during next step) ----
            {
                const half8 v = *(const half8*)&Hb[p][stile][srr][((sc ^ (srr & 7)) * 8)];
                *(half8*)(out1 + (size_t)t * (BATCH * 128) + out_off) = v;
            }
        }
    }
}

// ===================== Kernel 2: LSTM layer 2 + LN + FC =====================
// BT=16, 4 waves, grid=512 (2 blocks/CU). K = [h1(0:128) | h2(128:192)], 6 chunks.
// h1 tile prefetched TWO steps ahead (covers HBM latency before the barrier drain).
extern "C" __global__ __launch_bounds__(256, 2)
void lstm2_head_kernel(const _Float16* __restrict__ out1,
                       const float* __restrict__ Wih2, const float* __restrict__ Whh2,
                       const float* __restrict__ bih2, const float* __restrict__ bhh2,
                       const float* __restrict__ gamma, const float* __restrict__ beta,
                       const float* __restrict__ W1fc, const float* __restrict__ b1fc,
                       const float* __restrict__ W2fc, const float* __restrict__ b2fc,
                       float* __restrict__ out)
{
    __shared__ __align__(16) _Float16 A2h1[2][16][128];  // 16B chunk c of row r stored at c^(r&7)
    __shared__ __align__(16) _Float16 A2h2[2][16][72];   // row stride 144B (odd 16B count)
    __shared__ float h2f[16][68];
    __shared__ float nrm[16][68];

    const int tid  = threadIdx.x;
    const int lane = tid & 63;
    const int w    = tid >> 6;      // 0..3
    const int lrow = lane & 15;
    const int lgrp = lane >> 4;
    const int b0   = blockIdx.x * 16;

    half8 bf2[4][6];
    float bias2[4];
#pragma unroll
    for (int g = 0; g < 4; ++g) {
        const int n = g * 64 + w * 16 + lrow;
        bias2[g] = bih2[n] + bhh2[n];
#pragma unroll
        for (int ch = 0; ch < 6; ++ch) {
            half8 v;
#pragma unroll
            for (int j = 0; j < 8; ++j) {
                const int kk = ch * 32 + lgrp * 8 + j;
                v[j] = (_Float16)((kk < 128) ? Wih2[n * 128 + kk]
                                             : Whh2[n * 64 + (kk - 128)]);
            }
            bf2[g][ch] = v;
        }
    }

    for (int i = tid; i < 16 * 72 * 2; i += 256)
        (&A2h2[0][0][0])[i] = (_Float16)0.0f;

    const int prow = tid >> 4, pck = tid & 15;
    // stage t=0 tile; prefetch t=1, t=2
    {
        const half8 v = *(const half8*)(out1 + ((size_t)(b0 + prow)) * 128 + pck * 8);
        *(half8*)&A2h1[0][prow][((pck ^ (prow & 7)) * 8)] = v;
    }
    half8 pf1 = *(const half8*)(out1 + ((size_t)1 * BATCH + b0 + prow) * 128 + pck * 8);
    half8 pf2 = *(const half8*)(out1 + ((size_t)2 * BATCH + b0 + prow) * 128 + pck * 8);

    float c2[4] = {0.f, 0.f, 0.f, 0.f};
    __syncthreads();

    int cur = 0;
    for (int t = 0; t < TS; ++t) {
        const int nxt = cur ^ 1;
        f32x4 z[4];
#pragma unroll
        for (int g = 0; g < 4; ++g) {
            f32x4 acc = {bias2[g], bias2[g], bias2[g], bias2[g]};
#pragma unroll
            for (int ch = 0; ch < 6; ++ch) {
                half8 a;
                if (ch < 4) {
                    const int ckr = (ch * 4 + lgrp) ^ (lrow & 7);
                    a = *(const half8*)&A2h1[cur][lrow][ckr * 8];
                } else {
                    a = *(const half8*)&A2h2[cur][lrow][(ch - 4) * 32 + lgrp * 8];
                }
                acc = __builtin_amdgcn_mfma_f32_16x16x32_f16(a, bf2[g][ch], acc, 0, 0, 0);
            }
            z[g] = acc;
        }
        const int cell = w * 16 + lrow;
#pragma unroll
        for (int j = 0; j < 4; ++j) {
            const float iv = fast_sig (z[0][j]);
            const float fv = fast_sig (z[1][j]);
            const float gv = fast_tanh(z[2][j]);
            const float ov = fast_sig (z[3][j]);
            const float cn = fv * c2[j] + iv * gv;
            c2[j] = cn;
            const float h = ov * fast_tanh(cn);
            const int m = lgrp * 4 + j;
            A2h2[nxt][m][cell] = (_Float16)h;
            if (t == TS - 1) h2f[m][cell] = h;
        }
        if (t + 1 < TS)
            *(half8*)&A2h1[nxt][prow][((pck ^ (prow & 7)) * 8)] = pf1;
        pf1 = pf2;
        if (t + 3 < TS)
            pf2 = *(const half8*)(out1 + ((size_t)(t + 3) * BATCH + b0 + prow) * 128 + pck * 8);
        __syncthreads();
        cur = nxt;
    }

    // ---- epilogue: LayerNorm + FC1(relu) + FC2 ----
    {
        const int m = tid >> 4, q = tid & 15;
        const float v0 = h2f[m][q * 4 + 0];
        const float v1 = h2f[m][q * 4 + 1];
        const float v2 = h2f[m][q * 4 + 2];
        const float v3 = h2f[m][q * 4 + 3];
        float s = v0 + v1 + v2 + v3;
        s += __shfl_xor(s, 1); s += __shfl_xor(s, 2);
        s += __shfl_xor(s, 4); s += __shfl_xor(s, 8);
        const float mean = s * (1.0f / 64.0f);
        const float d0 = v0 - mean, d1 = v1 - mean, d2 = v2 - mean, d3 = v3 - mean;
        float vs = d0 * d0 + d1 * d1 + d2 * d2 + d3 * d3;
        vs += __shfl_xor(vs, 1); vs += __shfl_xor(vs, 2);
        vs += __shfl_xor(vs, 4); vs += __shfl_xor(vs, 8);
        const float rstd = rsqrtf(vs * (1.0f / 64.0f) + 1e-5f);
        const int i0 = q * 4;
        nrm[m][i0 + 0] = d0 * rstd * gamma[i0 + 0] + beta[i0 + 0];
        nrm[m][i0 + 1] = d1 * rstd * gamma[i0 + 1] + beta[i0 + 1];
        nrm[m][i0 + 2] = d2 * rstd * gamma[i0 + 2] + beta[i0 + 2];
        nrm[m][i0 + 3] = d3 * rstd * gamma[i0 + 3] + beta[i0 + 3];
    }
    __syncthreads();
    {
        const int o = tid & 31;
        const int mbase = tid >> 5;   // 0..7
#pragma unroll
        for (int rr = 0; rr < 2; ++rr) {
            const int m = mbase + rr * 8;
            float acc = b1fc[o];
#pragma unroll 8
            for (int k = 0; k < 64; ++k) acc += nrm[m][k] * W1fc[o * 64 + k];
            const float hv = fmaxf(acc, 0.0f);
            float p = hv * W2fc[o];
            p += __shfl_xor(p, 1); p += __shfl_xor(p, 2);
            p += __shfl_xor(p, 4); p += __shfl_xor(p, 8); p += __shfl_xor(p, 16);
            if (o == 0) out[b0 + m] = p + b2fc[0];
        }
    }
}

extern "C" void kernel_launch(void* const* d_in, const int* in_sizes, int n_in,
                              void* d_out, int out_size, void* d_ws, size_t ws_size,
                              hipStream_t stream) {
    (void)in_sizes; (void)n_in; (void)ws_size; (void)out_size;
    const float* x_p    = (const float*)d_in[0];
    const float* Wih1_p = (const float*)d_in[1];
    const float* Whh1_p = (const float*)d_in[2];
    const float* bih1_p = (const float*)d_in[3];
    const float* bhh1_p = (const float*)d_in[4];
    const float* Wih2_p = (const float*)d_in[5];
    const float* Whh2_p = (const float*)d_in[6];
    const float* bih2_p = (const float*)d_in[7];
    const float* bhh2_p = (const float*)d_in[8];
    const float* gamma_p = (const float*)d_in[9];
    const float* beta_p  = (const float*)d_in[10];
    const float* W1_p   = (const float*)d_in[11];
    const float* b1_p   = (const float*)d_in[12];
    const float* W2_p   = (const float*)d_in[13];
    const float* b2_p   = (const float*)d_in[14];
    float* out_p = (float*)d_out;

    _Float16* out1 = (_Float16*)d_ws;   // 20*8192*128*2 = 41.9 MB

    lstm1_kernel<<<dim3(BATCH / 32), dim3(512), 0, stream>>>(
        x_p, Wih1_p, Whh1_p, bih1_p, bhh1_p, out1);
    lstm2_head_kernel<<<dim3(BATCH / 16), dim3(256), 0, stream>>>(
        out1, Wih2_p, Whh2_p, bih2_p, bhh2_p,
        gamma_p, beta_p, W1_p, b1_p, W2_p, b2_p, out_p);
}